// Round 6
// baseline (1341.448 us; speedup 1.0000x reference)
//
#include <hip/hip_runtime.h>
#include <hip/hip_fp16.h>
#include <math.h>

// Problem constants
#define HD    1024      // hidden size
#define SEQL  512       // sequence length
#define NLAB  122       // labels
#define NWG   128       // workgroups in persistent recurrent role
#define TPW   512       // threads per WG
#define JPW   8         // h-columns (j) per workgroup  (NWG*JPW == HD)

// Workspace layout (bytes).
#define OFF_MSG   ((size_t)0)          // h msg: 2*1024 u64 (tag<<32|h_bits)    = 16384 B
#define OFF_HALL  ((size_t)16384)      // h_all: 512*1024 fp32                  = 2097152 B
#define OFF_GATES ((size_t)2113536)    // gates_x: 512*4096 fp32 (swizzled)     = 8388608 B
#define OFF_WR    ((size_t)10502144)   // W_r2: 4096*1024 fp32 (swizzled)       = 16777216 B
#define OFF_W1H   ((size_t)27279360)   // W1h: 4096*4096 fp16                   = 33554432 B
#define OFF_FH    ((size_t)60833792)   // F_h: 512*4096 fp16                    = 4194304 B
#define WS_NEED   ((size_t)65028096)
// done counters for the fused producer/consumer handshake (4 x u32, padded)
#define OFF_DONE  WS_NEED
#define WS_NEED_F (WS_NEED + 256)

typedef unsigned long long u64;
typedef _Float16 v8h __attribute__((ext_vector_type(8)));
typedef float v4f __attribute__((ext_vector_type(4)));
typedef float v2f __attribute__((ext_vector_type(2)));
typedef unsigned int v4u __attribute__((ext_vector_type(4)));

// Shared-memory union: lstm role uses the full struct; gates role only AsB.
// Total 152704 B -> exactly 1 WG/CU (160 KiB LDS) for both roles.
union SMem {
    struct {
        float4 W[16][TPW];     // 131072 B: recurrent weights, lane-contiguous
        float4 h4[256];        //   4096 B: h_{s-1}
        float  part[8][36];    //   1152 B: [wave][row] partials
        float  gxs[4096];      //  16384 B: current t-block's gates (128 x 32)
    } l;
    uint4 AsB[1024];           //  16384 B: GEMM staging (A 0..511, B 512..1023)
};

// ---------------------------------------------------------------------------
// Merged prep: one launch for W_r2, F_h, W1h (all independent elementwise).
//   b <  4096          : W_r2[g][i][t] = W_ih[.,4096+k] + W_hh  (R4 layout)
//   4096 <= b < 5120   : F_h = fp16(concat(x,hi))
//   5120 <= b < 13312  : W1h = fp16(W_ih[:, :4096])
static __device__ __forceinline__ uint4 pack8(float4 f0, float4 f1) {
    __half2 p0 = __floats2half2_rn(f0.x, f0.y);
    __half2 p1 = __floats2half2_rn(f0.z, f0.w);
    __half2 p2 = __floats2half2_rn(f1.x, f1.y);
    __half2 p3 = __floats2half2_rn(f1.z, f1.w);
    uint4 o;
    o.x = *(unsigned*)&p0; o.y = *(unsigned*)&p1;
    o.z = *(unsigned*)&p2; o.w = *(unsigned*)&p3;
    return o;
}

__global__ __launch_bounds__(256) void prep_all(const float* __restrict__ x,
                                                const float* __restrict__ hi,
                                                const float* __restrict__ W_ih,
                                                const float* __restrict__ W_hh,
                                                float* __restrict__ W_r2,
                                                uint4* __restrict__ F_h,
                                                uint4* __restrict__ W1h) {
    int b = blockIdx.x;
    int tid = threadIdx.x;
    if (b < 4096) {
        int o = b * 256 + tid;            // float4 index, < 1048576
        int g   = o >> 13;
        int i   = (o >> 9) & 15;
        int t   = o & 511;
        int row = t & 31;
        int kq  = t >> 5;
        int gate = row >> 3;
        int jj   = row & 7;
        int R = (gate << 10) + (g << 3) + jj;
        int k = (kq << 6) + (i << 2);
        float4 wa = *(const float4*)(W_ih + (size_t)R * 5120 + 4096 + k);
        float4 wb = *(const float4*)(W_hh + (size_t)R * 1024 + k);
        float4 out;
        out.x = wa.x + wb.x; out.y = wa.y + wb.y;
        out.z = wa.z + wb.z; out.w = wa.w + wb.w;
        *(float4*)(W_r2 + (size_t)o * 4) = out;
    } else if (b < 5120) {
        int o = (b - 4096) * 256 + tid;   // < 262144
        int t = o >> 9;
        int u = o & 511;
        const float* src = (u < 256) ? (x  + (size_t)t * 2048 + u * 8)
                                     : (hi + (size_t)t * 2048 + (u - 256) * 8);
        F_h[o] = pack8(*(const float4*)src, *(const float4*)(src + 4));
    } else {
        int o = (b - 5120) * 256 + tid;   // < 2097152
        int r = o >> 9;
        int u = o & 511;
        const float* src = W_ih + (size_t)r * 5120 + u * 8;
        W1h[o] = pack8(*(const float4*)src, *(const float4*)(src + 4));
    }
}

// ---------------------------------------------------------------------------
// Gates GEMM tile, 512-thread / 8-wave variant of the proven 4-wave kernel.
// Tile 128x128, BK=32, fp16 in / fp32 acc. Wave (wr,wc): wr=wv&1 (m-half),
// wc=wv>>2? no: wc=wv>>1 in [0,4) (n-quarter, 32 wide): acc[4][2].
// bid: n-tile = bid&31, t-block = bid>>5 (t-block-major so block 0 lands on
// the first 32 dispatched WGs and finishes first).
// Epilogue stores are AGENT-scope (write-through to coherence point) so the
// co-resident lstm WGs can read them; then done[tb] is bumped.
static __device__ void gates_tile(const uint4* __restrict__ F_u4,
                                  const uint4* __restrict__ W_u4,
                                  const float* __restrict__ b_ih,
                                  const float* __restrict__ b_hh,
                                  float* __restrict__ gates_x,
                                  unsigned* __restrict__ done,
                                  uint4* AsB, int bid, int tid) {
    const _Float16* Ash = (const _Float16*)AsB;   // 4096 halfs (slots 0..511)
    const _Float16* Bsh = Ash + 4096;             // slots 512..1023
    const int wv   = tid >> 6;
    const int lane = tid & 63;
    const int wr   = wv & 1;             // m half (64 rows)
    const int wc   = wv >> 1;            // n quarter (32 cols), 0..3
    const int n0 = (bid & 31) * 128;
    const int tb = bid >> 5;
    const int t0 = tb * 128;

    // staging: slot u in [0,512): row = u>>2, kpart = u&3; one A + one B per thread
    const int u = tid;
    const uint4* aSrc = F_u4 + (size_t)(t0 + (u >> 2)) * 512 + (u & 3);
    const uint4* bSrc = W_u4 + (size_t)(n0 + (u >> 2)) * 512 + (u & 3);

    v4f acc[4][2];
    #pragma unroll
    for (int mi = 0; mi < 4; ++mi)
        #pragma unroll
        for (int ni = 0; ni < 2; ++ni)
            acc[mi][ni] = (v4f){0.f, 0.f, 0.f, 0.f};

    const int aoff = (wr * 64 + (lane & 15)) * 32 + (lane >> 4) * 8;
    const int boff = (wc * 32 + (lane & 15)) * 32 + (lane >> 4) * 8;

    for (int it = 0; it < 128; ++it) {    // kb = it*32, advance 4 uint4/row
        uint4 a = aSrc[it * 4];
        uint4 b = bSrc[it * 4];
        __syncthreads();                  // prior iter's frag reads done
        AsB[u]       = a;
        AsB[512 + u] = b;
        __syncthreads();
        v8h a8[4], b8[2];
        #pragma unroll
        for (int mi = 0; mi < 4; ++mi)
            a8[mi] = *(const v8h*)(Ash + aoff + mi * 16 * 32);
        #pragma unroll
        for (int ni = 0; ni < 2; ++ni)
            b8[ni] = *(const v8h*)(Bsh + boff + ni * 16 * 32);
        #pragma unroll
        for (int mi = 0; mi < 4; ++mi)
            #pragma unroll
            for (int ni = 0; ni < 2; ++ni)
                acc[mi][ni] = __builtin_amdgcn_mfma_f32_16x16x32_f16(
                                  a8[mi], b8[ni], acc[mi][ni], 0, 0, 0);
    }

    // epilogue: row(t) = t0 + wr*64 + mi*16 + (lane>>4)*4 + reg
    //           col(r) = n0 + wc*32 + ni*16 + (lane&15); R4 swizzle on store.
    #pragma unroll
    for (int ni = 0; ni < 2; ++ni) {
        int r = n0 + wc * 32 + ni * 16 + (lane & 15);
        int sidx = ((r & 1023) >> 3) * 32 + (r >> 10) * 8 + (r & 7);
        float bias = b_ih[r] + b_hh[r];
        #pragma unroll
        for (int mi = 0; mi < 4; ++mi) {
            int trow = t0 + wr * 64 + mi * 16 + ((lane >> 4) << 2);
            #pragma unroll
            for (int reg = 0; reg < 4; ++reg)
                __hip_atomic_store(gates_x + (size_t)(trow + reg) * 4096 + sidx,
                                   acc[mi][ni][reg] + bias,
                                   __ATOMIC_RELAXED, __HIP_MEMORY_SCOPE_AGENT);
        }
    }
    // barrier waits vmcnt(0): all threads' write-through stores are at the
    // coherence point before the counter bump.
    __syncthreads();
    if (tid == 0)
        __hip_atomic_fetch_add(done + tb, 1u,
                               __ATOMIC_RELEASE, __HIP_MEMORY_SCOPE_AGENT);
}

// ---------------------------------------------------------------------------
// Persistent recurrent role — best-measured composite (R5 886us structure):
//   * R5 poll verbatim: 2 back-to-back dwordx4 sc1 samples, fully drained.
//   * R5 gx-from-LDS: t-block of gates staged into LDS (16 KB), refreshed
//     every 128 steps after a done[tb] handshake (fused mode).
//   * R6 weights-in-LDS read to regs pre-poll (latency under the wait).
//   * wave-local h exchange (no pre-matvec barrier), per-lane activations,
//     single barrier per step, single mailbox (R9 replication reverted).
static __device__ void lstm_body(const float* __restrict__ gates_x,
                                 const float* __restrict__ W_r2,
                                 float* __restrict__ h_all,
                                 u64* h_msg,
                                 unsigned* done,      // nullptr: gates ready
                                 SMem* sm, int g, int tid) {
    const int row = tid & 31;    // gate = row>>3, jj = row&7
    const int kq  = tid >> 5;    // k-slice [kq*64, kq*64+64)
    float4 (*W_lds)[TPW] = sm->l.W;
    float4* h_s4 = sm->l.h4;
    float (*partial)[36] = sm->l.part;
    float* gxs = sm->l.gxs;
    float* h_sf = (float*)h_s4;

    {
        const float4* Wp = (const float4*)W_r2 + (size_t)g * 8192;
        #pragma unroll
        for (int i = 0; i < 16; ++i)
            W_lds[i][tid] = Wp[i * TPW + tid];
    }
    __syncthreads();

    float c = 0.f;
    int budget = 4000000;

    for (int s = 0; s < SEQL; ++s) {
        // --- t-block boundary: handshake with gates producers, then stage
        // this block's 16 KB of gates into LDS (ordinary loads; producers
        // stored agent-scope write-through). --------------------------------
        if ((s & 127) == 0) {
            int tb = s >> 7;
            if (done) {
                if (tid == 0) {
                    int sp = 20000000;
                    while (__hip_atomic_load(done + tb, __ATOMIC_ACQUIRE,
                                             __HIP_MEMORY_SCOPE_AGENT) < 32u) {
                        if (--sp < 0) break;
                        __builtin_amdgcn_s_sleep(8);
                    }
                }
                __syncthreads();
            }
            float4* gxs4 = (float4*)gxs;
            #pragma unroll
            for (int k = 0; k < 2; ++k) {
                int o4 = tid + k * 512;          // [0,1024)
                int t  = o4 >> 3, c4 = o4 & 7;
                gxs4[o4] = *(const float4*)(gates_x + (size_t)(s + t) * 4096
                                            + g * 32 + c4 * 4);
            }
            __syncthreads();
        }

        // --- pre-poll: gx from LDS + weight fragments LDS->reg; both are
        // h-independent, latency hides under the mailbox wait. --------------
        float gx = 0.f;
        if (tid < 32) gx = gxs[(s & 127) * 32 + tid];

        asm volatile("" ::: "memory");
        float4 w[16];
        #pragma unroll
        for (int i = 0; i < 16; ++i)
            w[i] = W_lds[i][tid];
        asm volatile("" ::: "memory");

        // --- R5 poll verbatim: two coalesced 16B device-scope samples per
        // round, fully drained (nothing in flight at the break). ------------
        {
            const u64 addr = (u64)(h_msg + (size_t)(s & 1) * HD + tid * 2);
            const unsigned want = (unsigned)s;
            v4u ra, rb;
            for (;;) {
                asm volatile(
                    "global_load_dwordx4 %0, %2, off sc1\n\t"
                    "global_load_dwordx4 %1, %2, off sc1\n\t"
                    "s_waitcnt vmcnt(0)"
                    : "=&v"(ra), "=&v"(rb)
                    : "v"(addr)
                    : "memory");
                if (ra.y == want && ra.w == want) break;
                if (rb.y == want && rb.w == want) { ra = rb; break; }
                if (--budget < 0) { ra = rb; break; }
            }
            ((v2f*)h_sf)[tid] = (v2f){__uint_as_float(ra.x), __uint_as_float(ra.z)};
        }
        // Wave-local exchange: this wave's lanes wrote exactly the 128 floats
        // this wave's matvec reads; same-wave DS ops execute in order, so no
        // barrier — only a compiler reordering fence.
        asm volatile("" ::: "memory");

        float a0 = 0.f, a1 = 0.f, a2 = 0.f, a3 = 0.f;
        #pragma unroll
        for (int i = 0; i < 16; ++i) {
            float4 h4 = h_s4[kq * 16 + i];
            a0 += w[i].x * h4.x;
            a1 += w[i].y * h4.y;
            a2 += w[i].z * h4.z;
            a3 += w[i].w * h4.w;
        }
        float p = (a0 + a1) + (a2 + a3);
        p += __shfl_xor(p, 32, 64);
        if ((tid & 32) == 0)
            partial[tid >> 6][row] = p;
        __syncthreads();

        if (tid < 32) {
            float sum = gx;
            #pragma unroll
            for (int q = 0; q < 8; ++q) sum += partial[q][tid];
            // Per-lane activation, bitwise-identical formulas:
            // rows 0-7 i, 8-15 f (sigmoid), 16-23 g (tanh), 24-31 o (sigmoid)
            bool isg = ((tid >> 3) == 2);
            float e   = __expf(isg ? -2.f * sum : -sum);
            float act = isg ? (2.f / (1.f + e) - 1.f) : (1.f / (1.f + e));
            int jj = tid & 7;
            float sf = __shfl(act,  8 + jj, 64);
            float tg = __shfl(act, 16 + jj, 64);
            float so = __shfl(act, 24 + jj, 64);
            if (tid < 8) {
                float si = act;
                c = sf * c + si * tg;
                float th = 2.f / (1.f + __expf(-2.f * c)) - 1.f;
                float h = so * th;
                int j = g * JPW + tid;
                h_all[(size_t)s * HD + j] = h;
                u64 m = ((u64)(unsigned)(s + 1) << 32)
                      | (u64)__float_as_uint(h);
                __hip_atomic_store(h_msg + (size_t)((s + 1) & 1) * HD + j, m,
                                   __ATOMIC_RELAXED, __HIP_MEMORY_SCOPE_AGENT);
            }
        }
    }
}

// ---------------------------------------------------------------------------
// Fused kernel: 256 WGs, 1 per CU (152704 B LDS). WGs 0..127 = gates GEMM
// (t-block-major), WGs 128..255 = persistent lstm. Deadlock-free by capacity:
// all 256 WGs are co-resident (1 WG/CU on 256 CUs); gates WGs never wait.
__global__ __launch_bounds__(512, 1) void gates_lstm_fused(
        const uint4* __restrict__ F_u4, const uint4* __restrict__ W_u4,
        const float* __restrict__ b_ih, const float* __restrict__ b_hh,
        float* __restrict__ gates_x,
        const float* __restrict__ W_r2, float* __restrict__ h_all,
        u64* h_msg, unsigned* done) {
    __shared__ SMem sm;
    const int tid = threadIdx.x;
    if (blockIdx.x < 128)
        gates_tile(F_u4, W_u4, b_ih, b_hh, gates_x, done, sm.AsB,
                   blockIdx.x, tid);
    else
        lstm_body(gates_x, W_r2, h_all, h_msg, done, &sm,
                  blockIdx.x - 128, tid);
}

// Standalone lstm (fallback path: gates already computed serially).
__global__ __launch_bounds__(512, 1) void lstm_only(
        const float* __restrict__ gates_x, const float* __restrict__ W_r2,
        float* __restrict__ h_all, u64* h_msg) {
    __shared__ SMem sm;
    lstm_body(gates_x, W_r2, h_all, h_msg, nullptr, &sm,
              blockIdx.x, threadIdx.x);
}

// ---------------------------------------------------------------------------
// Fallback fp32 VALU gates GEMM (used only if ws_size < WS_NEED).
__global__ __launch_bounds__(256) void gates_gemm_f32(const float* __restrict__ x,
                                                      const float* __restrict__ hi,
                                                      const float* __restrict__ W_ih,
                                                      const float* __restrict__ b_ih,
                                                      const float* __restrict__ b_hh,
                                                      float* __restrict__ gates_x) {
    __shared__ float As[16][68];
    __shared__ float Bs[16][68];
    const int tid = threadIdx.x;
    const int r0 = blockIdx.x * 64;
    const int t0 = blockIdx.y * 64;
    const int tx = tid & 15, ty = tid >> 4;
    const int l   = tid & 63;
    const int kq4 = tid >> 6;

    float acc[4][4] = {};
    for (int kb = 0; kb < 4096; kb += 16) {
        int k = kb + kq4 * 4;
        const float* asrc = (k < 2048) ? (x  + (size_t)(t0 + l) * 2048 + k)
                                       : (hi + (size_t)(t0 + l) * 2048 + (k - 2048));
        float4 a4 = *(const float4*)asrc;
        float4 b4 = *(const float4*)(W_ih + (size_t)(r0 + l) * 5120 + k);
        __syncthreads();
        As[kq4 * 4 + 0][l] = a4.x; As[kq4 * 4 + 1][l] = a4.y;
        As[kq4 * 4 + 2][l] = a4.z; As[kq4 * 4 + 3][l] = a4.w;
        Bs[kq4 * 4 + 0][l] = b4.x; Bs[kq4 * 4 + 1][l] = b4.y;
        Bs[kq4 * 4 + 2][l] = b4.z; Bs[kq4 * 4 + 3][l] = b4.w;
        __syncthreads();
        #pragma unroll
        for (int kk = 0; kk < 16; ++kk) {
            float4 av = *(const float4*)&As[kk][ty * 4];
            float4 bv = *(const float4*)&Bs[kk][tx * 4];
            float a_[4] = {av.x, av.y, av.z, av.w};
            float b_[4] = {bv.x, bv.y, bv.z, bv.w};
            #pragma unroll
            for (int i = 0; i < 4; ++i)
                #pragma unroll
                for (int j = 0; j < 4; ++j)
                    acc[i][j] += a_[i] * b_[j];
        }
    }
    int r = r0 + tx * 4;
    float bias[4];
    #pragma unroll
    for (int j = 0; j < 4; ++j) bias[j] = b_ih[r + j] + b_hh[r + j];
    int gate = r >> 10;
    int g    = (r & 1023) >> 3;
    int jj   = r & 7;
    int sidx = g * 32 + gate * 8 + jj;
    #pragma unroll
    for (int i = 0; i < 4; ++i) {
        float4 o;
        o.x = acc[i][0] + bias[0]; o.y = acc[i][1] + bias[1];
        o.z = acc[i][2] + bias[2]; o.w = acc[i][3] + bias[3];
        *(float4*)(gates_x + (size_t)(t0 + ty * 4 + i) * 4096 + sidx) = o;
    }
}

// ---------------------------------------------------------------------------
// out[t][lab] = b_fc[lab] + sum_k h_all[t][k] * W_fc[lab][k]
// 4 timesteps per block: W_fc global traffic /4 vs the 1-t version.
__global__ __launch_bounds__(128) void fc_out(const float* __restrict__ h_all,
                                              const float* __restrict__ W_fc,
                                              const float* __restrict__ b_fc,
                                              float* __restrict__ out) {
    const int t0 = blockIdx.x * 4;          // 128 blocks x 4 t
    const int tid = threadIdx.x;
    __shared__ float4 h_s[1024];            // 16 KB: 4 rows of h
    const float4* hsrc = (const float4*)(h_all + (size_t)t0 * HD);
    #pragma unroll
    for (int i = 0; i < 8; ++i)
        h_s[tid + i * 128] = hsrc[tid + i * 128];
    __syncthreads();
    if (tid < NLAB) {
        float b = b_fc[tid];
        float acc0 = b, acc1 = b, acc2 = b, acc3 = b;
        const float4* wp = (const float4*)(W_fc + (size_t)tid * HD);
        #pragma unroll 4
        for (int k4 = 0; k4 < 256; ++k4) {
            float4 w = wp[k4];
            float4 h0 = h_s[k4];
            float4 h1 = h_s[256 + k4];
            float4 h2 = h_s[512 + k4];
            float4 h3 = h_s[768 + k4];
            acc0 += w.x*h0.x + w.y*h0.y + w.z*h0.z + w.w*h0.w;
            acc1 += w.x*h1.x + w.y*h1.y + w.z*h1.z + w.w*h1.w;
            acc2 += w.x*h2.x + w.y*h2.y + w.z*h2.z + w.w*h2.w;
            acc3 += w.x*h3.x + w.y*h3.y + w.z*h3.z + w.w*h3.w;
        }
        out[(size_t)(t0 + 0) * NLAB + tid] = acc0;
        out[(size_t)(t0 + 1) * NLAB + tid] = acc1;
        out[(size_t)(t0 + 2) * NLAB + tid] = acc2;
        out[(size_t)(t0 + 3) * NLAB + tid] = acc3;
    }
}

// ---------------------------------------------------------------------------
extern "C" void kernel_launch(void* const* d_in, const int* in_sizes, int n_in,
                              void* d_out, int out_size, void* d_ws, size_t ws_size,
                              hipStream_t stream) {
    const float* x    = (const float*)d_in[0];
    const float* hi   = (const float*)d_in[1];
    const float* W_ih = (const float*)d_in[2];
    const float* W_hh = (const float*)d_in[3];
    const float* b_ih = (const float*)d_in[4];
    const float* b_hh = (const float*)d_in[5];
    const float* W_fc = (const float*)d_in[6];
    const float* b_fc = (const float*)d_in[7];
    float* out = (float*)d_out;

    char* ws = (char*)d_ws;
    u64*      h_msg   = (u64*)(ws + OFF_MSG);
    float*    h_all   = (float*)(ws + OFF_HALL);
    float*    gates_x = (float*)(ws + OFF_GATES);
    float*    W_r2    = (float*)(ws + OFF_WR);
    uint4*    W1h     = (uint4*)(ws + OFF_W1H);
    uint4*    F_h     = (uint4*)(ws + OFF_FH);
    unsigned* done    = (unsigned*)(ws + OFF_DONE);

    // zero the mailbox (h_{-1}=0, tag 0) — ws re-poisoned 0xAA each call
    hipMemsetAsync(h_msg, 0, 16384, stream);

    if (ws_size >= WS_NEED_F) {
        hipMemsetAsync(done, 0, 256, stream);
        prep_all<<<13312, 256, 0, stream>>>(x, hi, W_ih, W_hh, W_r2, F_h, W1h);
        gates_lstm_fused<<<256, TPW, 0, stream>>>(F_h, W1h, b_ih, b_hh, gates_x,
                                                  W_r2, h_all, h_msg, done);
    } else {
        // small-ws fallback: serial fp32 gates GEMM + standalone lstm
        prep_all<<<4096, 256, 0, stream>>>(x, hi, W_ih, W_hh, W_r2, F_h, W1h);
        dim3 gg(64, 8);
        gates_gemm_f32<<<gg, 256, 0, stream>>>(x, hi, W_ih, b_ih, b_hh, gates_x);
        lstm_only<<<NWG, TPW, 0, stream>>>(gates_x, W_r2, h_all, h_msg);
    }

    fc_out<<<SEQL / 4, 128, 0, stream>>>(h_all, W_fc, b_fc, out);
}

// Round 7
// 1245.876 us; speedup vs baseline: 1.0767x; 1.0767x over previous
//
#include <hip/hip_runtime.h>
#include <hip/hip_fp16.h>
#include <math.h>

// Problem constants
#define HD    1024      // hidden size
#define SEQL  512       // sequence length
#define NLAB  122       // labels
#define NWG   128      // workgroups in persistent recurrent kernel
#define TPW   512       // threads per WG
#define JPW   8         // h-columns (j) per workgroup  (NWG*JPW == HD)

// Workspace layout (bytes).
#define OFF_MSG   ((size_t)0)          // h msg: 2*1024 u64 (tag<<32|h_bits)    = 16384 B
#define OFF_HALL  ((size_t)16384)      // h_all: 512*1024 fp32                  = 2097152 B
#define OFF_GATES ((size_t)2113536)    // gates_x: 512*4096 fp32 (swizzled)     = 8388608 B
#define OFF_WR    ((size_t)10502144)   // W_r2: 4096*1024 fp32 (swizzled)       = 16777216 B
#define OFF_W1H   ((size_t)27279360)   // W1h: 4096*4096 fp16                   = 33554432 B
#define OFF_FH    ((size_t)60833792)   // F_h: 512*4096 fp16                    = 4194304 B
#define WS_NEED   ((size_t)65028096)

typedef unsigned long long u64;
typedef _Float16 v8h __attribute__((ext_vector_type(8)));
typedef float v4f __attribute__((ext_vector_type(4)));
typedef float v2f __attribute__((ext_vector_type(2)));
typedef unsigned int v4u __attribute__((ext_vector_type(4)));

// ---------------------------------------------------------------------------
// Merged prep: ONE launch for W_r2, mailbox zeroing, F_h, W1h.
//   b <  4096          : W_r2[g][i][t] = W_ih[.,4096+k] + W_hh  (R4 layout)
//   b == 4096          : zero h_msg (2048 u64)
//   4097 <= b < 5121   : F_h = fp16(concat(x,hi))
//   b >= 5121          : W1h = fp16(W_ih[:, :4096])
// Fallback (small ws) launches only 4097 blocks (no F_h/W1h writes).
static __device__ __forceinline__ uint4 pack8(float4 f0, float4 f1) {
    __half2 p0 = __floats2half2_rn(f0.x, f0.y);
    __half2 p1 = __floats2half2_rn(f0.z, f0.w);
    __half2 p2 = __floats2half2_rn(f1.x, f1.y);
    __half2 p3 = __floats2half2_rn(f1.z, f1.w);
    uint4 o;
    o.x = *(unsigned*)&p0; o.y = *(unsigned*)&p1;
    o.z = *(unsigned*)&p2; o.w = *(unsigned*)&p3;
    return o;
}

__global__ __launch_bounds__(256) void prep_all(const float* __restrict__ x,
                                                const float* __restrict__ hi,
                                                const float* __restrict__ W_ih,
                                                const float* __restrict__ W_hh,
                                                float* __restrict__ W_r2,
                                                uint4* __restrict__ F_h,
                                                uint4* __restrict__ W1h,
                                                u64* __restrict__ h_msg) {
    int b = blockIdx.x;
    int tid = threadIdx.x;
    if (b < 4096) {
        int o = b * 256 + tid;            // float4 index, < 1048576
        int g   = o >> 13;
        int i   = (o >> 9) & 15;
        int t   = o & 511;
        int row = t & 31;
        int kq  = t >> 5;
        int gate = row >> 3;
        int jj   = row & 7;
        int R = (gate << 10) + (g << 3) + jj;
        int k = (kq << 6) + (i << 2);
        float4 wa = *(const float4*)(W_ih + (size_t)R * 5120 + 4096 + k);
        float4 wb = *(const float4*)(W_hh + (size_t)R * 1024 + k);
        float4 out;
        out.x = wa.x + wb.x; out.y = wa.y + wb.y;
        out.z = wa.z + wb.z; out.w = wa.w + wb.w;
        *(float4*)(W_r2 + (size_t)o * 4) = out;
    } else if (b == 4096) {
        // mailbox zero: h_{-1}=0 with tag 0 (ws re-poisoned 0xAA each call)
        #pragma unroll
        for (int i = 0; i < 8; ++i)
            h_msg[tid * 8 + i] = 0ull;
    } else if (b < 5121) {
        int o = (b - 4097) * 256 + tid;   // < 262144
        int t = o >> 9;
        int u = o & 511;
        const float* src = (u < 256) ? (x  + (size_t)t * 2048 + u * 8)
                                     : (hi + (size_t)t * 2048 + (u - 256) * 8);
        F_h[o] = pack8(*(const float4*)src, *(const float4*)(src + 4));
    } else {
        int o = (b - 5121) * 256 + tid;   // < 2097152
        int r = o >> 9;
        int u = o & 511;
        const float* src = W_ih + (size_t)r * 5120 + u * 8;
        W1h[o] = pack8(*(const float4*)src, *(const float4*)(src + 4));
    }
}

// ---------------------------------------------------------------------------
// MFMA gates GEMM — R2-proven 4-wave version verbatim (0 bank conflicts).
// G[t][r] = bias[r] + sum_k F[t][k]*W1[r][k]; 128x128 tile, BK=32.
// Store to the R4-swizzled gates_x layout:
//   sidx(r) = ((r&1023)>>3)*32 + (r>>10)*8 + (r&7)
__global__ __launch_bounds__(256) void gates_mfma(const uint4* __restrict__ F_u4,
                                                  const uint4* __restrict__ W_u4,
                                                  const float* __restrict__ b_ih,
                                                  const float* __restrict__ b_hh,
                                                  float* __restrict__ gates_x) {
    __shared__ uint4 AsB[1024];          // As = [0,512), Bs = [512,1024)
    const _Float16* Ash = (const _Float16*)AsB;          // 4096 halfs
    const _Float16* Bsh = Ash + 4096;
    const int tid  = threadIdx.x;
    const int wv   = tid >> 6;
    const int lane = tid & 63;
    const int wr   = wv & 1;             // m quadrant
    const int wc   = wv >> 1;            // n quadrant
    const int n0 = blockIdx.x * 128;
    const int t0 = blockIdx.y * 128;

    // staging map: uint4 slot u in [0,512): row = u>>2, kpart = u&3
    const int u0 = tid * 2, u1 = tid * 2 + 1;
    const uint4* aSrc0 = F_u4 + (size_t)(t0 + (u0 >> 2)) * 512 + (u0 & 3);
    const uint4* aSrc1 = F_u4 + (size_t)(t0 + (u1 >> 2)) * 512 + (u1 & 3);
    const uint4* bSrc0 = W_u4 + (size_t)(n0 + (u0 >> 2)) * 512 + (u0 & 3);
    const uint4* bSrc1 = W_u4 + (size_t)(n0 + (u1 >> 2)) * 512 + (u1 & 3);

    v4f acc[4][4];
    #pragma unroll
    for (int mi = 0; mi < 4; ++mi)
        #pragma unroll
        for (int ni = 0; ni < 4; ++ni)
            acc[mi][ni] = (v4f){0.f, 0.f, 0.f, 0.f};

    const int aoff = (wr * 64 + (lane & 15)) * 32 + (lane >> 4) * 8;
    const int boff = (wc * 64 + (lane & 15)) * 32 + (lane >> 4) * 8;

    for (int it = 0; it < 128; ++it) {    // kb = it*32, advance 4 uint4/row
        uint4 a0 = aSrc0[it * 4], a1 = aSrc1[it * 4];
        uint4 b0 = bSrc0[it * 4], b1 = bSrc1[it * 4];
        __syncthreads();                  // prior iter's frag reads done
        AsB[u0]       = a0; AsB[u1]       = a1;
        AsB[512 + u0] = b0; AsB[512 + u1] = b1;
        __syncthreads();
        v8h a8[4], b8[4];
        #pragma unroll
        for (int mi = 0; mi < 4; ++mi)
            a8[mi] = *(const v8h*)(Ash + aoff + mi * 16 * 32);
        #pragma unroll
        for (int ni = 0; ni < 4; ++ni)
            b8[ni] = *(const v8h*)(Bsh + boff + ni * 16 * 32);
        #pragma unroll
        for (int mi = 0; mi < 4; ++mi)
            #pragma unroll
            for (int ni = 0; ni < 4; ++ni)
                acc[mi][ni] = __builtin_amdgcn_mfma_f32_16x16x32_f16(
                                  a8[mi], b8[ni], acc[mi][ni], 0, 0, 0);
    }

    // epilogue: C row (t) = t0 + wr*64 + mi*16 + (lane>>4)*4 + reg
    //           C col (r) = n0 + wc*64 + ni*16 + (lane&15)
    #pragma unroll
    for (int ni = 0; ni < 4; ++ni) {
        int r = n0 + wc * 64 + ni * 16 + (lane & 15);
        int sidx = ((r & 1023) >> 3) * 32 + (r >> 10) * 8 + (r & 7);
        float bias = b_ih[r] + b_hh[r];
        #pragma unroll
        for (int mi = 0; mi < 4; ++mi) {
            int tb = t0 + wr * 64 + mi * 16 + ((lane >> 4) << 2);
            #pragma unroll
            for (int reg = 0; reg < 4; ++reg)
                gates_x[(size_t)(tb + reg) * 4096 + sidx] = acc[mi][ni][reg] + bias;
        }
    }
}

// ---------------------------------------------------------------------------
// Fallback fp32 VALU gates GEMM (used only if ws_size < WS_NEED).
__global__ __launch_bounds__(256) void gates_gemm_f32(const float* __restrict__ x,
                                                      const float* __restrict__ hi,
                                                      const float* __restrict__ W_ih,
                                                      const float* __restrict__ b_ih,
                                                      const float* __restrict__ b_hh,
                                                      float* __restrict__ gates_x) {
    __shared__ float As[16][68];
    __shared__ float Bs[16][68];
    const int tid = threadIdx.x;
    const int r0 = blockIdx.x * 64;
    const int t0 = blockIdx.y * 64;
    const int tx = tid & 15, ty = tid >> 4;
    const int l   = tid & 63;
    const int kq4 = tid >> 6;

    float acc[4][4] = {};
    for (int kb = 0; kb < 4096; kb += 16) {
        int k = kb + kq4 * 4;
        const float* asrc = (k < 2048) ? (x  + (size_t)(t0 + l) * 2048 + k)
                                       : (hi + (size_t)(t0 + l) * 2048 + (k - 2048));
        float4 a4 = *(const float4*)asrc;
        float4 b4 = *(const float4*)(W_ih + (size_t)(r0 + l) * 5120 + k);
        __syncthreads();
        As[kq4 * 4 + 0][l] = a4.x; As[kq4 * 4 + 1][l] = a4.y;
        As[kq4 * 4 + 2][l] = a4.z; As[kq4 * 4 + 3][l] = a4.w;
        Bs[kq4 * 4 + 0][l] = b4.x; Bs[kq4 * 4 + 1][l] = b4.y;
        Bs[kq4 * 4 + 2][l] = b4.z; Bs[kq4 * 4 + 3][l] = b4.w;
        __syncthreads();
        #pragma unroll
        for (int kk = 0; kk < 16; ++kk) {
            float4 av = *(const float4*)&As[kk][ty * 4];
            float4 bv = *(const float4*)&Bs[kk][tx * 4];
            float a_[4] = {av.x, av.y, av.z, av.w};
            float b_[4] = {bv.x, bv.y, bv.z, bv.w};
            #pragma unroll
            for (int i = 0; i < 4; ++i)
                #pragma unroll
                for (int j = 0; j < 4; ++j)
                    acc[i][j] += a_[i] * b_[j];
        }
    }
    int r = r0 + tx * 4;
    float bias[4];
    #pragma unroll
    for (int j = 0; j < 4; ++j) bias[j] = b_ih[r + j] + b_hh[r + j];
    int gate = r >> 10;
    int g    = (r & 1023) >> 3;
    int jj   = r & 7;
    int sidx = g * 32 + gate * 8 + jj;
    #pragma unroll
    for (int i = 0; i < 4; ++i) {
        float4 o;
        o.x = acc[i][0] + bias[0]; o.y = acc[i][1] + bias[1];
        o.z = acc[i][2] + bias[2]; o.w = acc[i][3] + bias[3];
        *(float4*)(gates_x + (size_t)(t0 + ty * 4 + i) * 4096 + sidx) = o;
    }
}

// ---------------------------------------------------------------------------
// Persistent recurrent kernel + fused FC tail — R11.
//   lstm phase: R5/R6 best-measured composite verbatim (886-896 us):
//     * weights in LDS (R4 layout), read to regs PRE-POLL each step;
//     * gates t-block (16 KB) staged to LDS every 128 steps;
//     * R5 poll: two back-to-back dwordx4 sc1 samples, fully drained;
//     * wave-local h exchange (no pre-matvec barrier), per-lane activations,
//       single barrier per step.
//   Changes for the fused FC tail:
//     * h_all stores are agent-scope write-through (plain stores are NOT
//       cross-XCD coherent without a kernel boundary);
//     * the FINAL mailbox publish (tag 512) is RELEASE, ordering each
//       producer's h_all writes before its tag;
//     * after the loop: poll parity-0 for tag==512, stage 4 rows of h via
//       sc1 loads into the gxs LDS area, compute out[t0..t0+3][0..121]
//       (fc_out-4t structure, W_fc read once per WG).
__global__ __launch_bounds__(512, 1) void lstm_fc(const float* __restrict__ gates_x,
                                                  const float* __restrict__ W_r2,
                                                  float* __restrict__ h_all,
                                                  u64* h_msg,
                                                  const float* __restrict__ W_fc,
                                                  const float* __restrict__ b_fc,
                                                  float* __restrict__ out) {
    const int g   = blockIdx.x;
    const int tid = threadIdx.x;
    const int row = tid & 31;    // gate = row>>3, jj = row&7
    const int kq  = tid >> 5;    // k-slice [kq*64, kq*64+64)
    __shared__ float4 W_lds[16][TPW];   // 131072 B, lane-contiguous
    __shared__ float4 h_s4[256];        // h_{s-1}
    __shared__ float  partial[8][36];   // [wave][row]
    __shared__ float  gxs[4096];        // 16 KB: gates t-block / fc h staging
    float* h_sf = (float*)h_s4;

    {
        const float4* Wp = (const float4*)W_r2 + (size_t)g * 8192;
        #pragma unroll
        for (int i = 0; i < 16; ++i)
            W_lds[i][tid] = Wp[i * TPW + tid];
    }
    __syncthreads();

    float c = 0.f;
    int budget = 4000000;

    for (int s = 0; s < SEQL; ++s) {
        // --- t-block boundary: stage 128 steps x 32 gate-rows into LDS.
        // Write-after-read safe: every wave's last gxs read (step s-1
        // pre-poll) precedes the step s-1 mid barrier. -----------------------
        if ((s & 127) == 0) {
            float4* gxs4 = (float4*)gxs;
            #pragma unroll
            for (int k = 0; k < 2; ++k) {
                int o4 = tid + k * 512;          // [0,1024)
                int t  = o4 >> 3, c4 = o4 & 7;
                gxs4[o4] = *(const float4*)(gates_x + (size_t)(s + t) * 4096
                                            + g * 32 + c4 * 4);
            }
            __syncthreads();
        }

        // --- pre-poll: gx from LDS + weight fragments LDS->reg; both
        // h-independent, latency hides under the mailbox wait. --------------
        float gx = 0.f;
        if (tid < 32) gx = gxs[(s & 127) * 32 + tid];

        asm volatile("" ::: "memory");
        float4 w[16];
        #pragma unroll
        for (int i = 0; i < 16; ++i)
            w[i] = W_lds[i][tid];
        asm volatile("" ::: "memory");

        // --- R5 poll verbatim: two coalesced 16B device-scope samples per
        // round, fully drained (nothing in flight at the break). ------------
        {
            const u64 addr = (u64)(h_msg + (size_t)(s & 1) * HD + tid * 2);
            const unsigned want = (unsigned)s;
            v4u ra, rb;
            for (;;) {
                asm volatile(
                    "global_load_dwordx4 %0, %2, off sc1\n\t"
                    "global_load_dwordx4 %1, %2, off sc1\n\t"
                    "s_waitcnt vmcnt(0)"
                    : "=&v"(ra), "=&v"(rb)
                    : "v"(addr)
                    : "memory");
                if (ra.y == want && ra.w == want) break;
                if (rb.y == want && rb.w == want) { ra = rb; break; }
                if (--budget < 0) { ra = rb; break; }
            }
            ((v2f*)h_sf)[tid] = (v2f){__uint_as_float(ra.x), __uint_as_float(ra.z)};
        }
        // Wave-local exchange: this wave's lanes wrote exactly the 128 floats
        // this wave's matvec reads; same-wave DS ops execute in order, so no
        // barrier — only a compiler reordering fence.
        asm volatile("" ::: "memory");

        float a0 = 0.f, a1 = 0.f, a2 = 0.f, a3 = 0.f;
        #pragma unroll
        for (int i = 0; i < 16; ++i) {
            float4 h4 = h_s4[kq * 16 + i];
            a0 += w[i].x * h4.x;
            a1 += w[i].y * h4.y;
            a2 += w[i].z * h4.z;
            a3 += w[i].w * h4.w;
        }
        float p = (a0 + a1) + (a2 + a3);
        p += __shfl_xor(p, 32, 64);
        if ((tid & 32) == 0)
            partial[tid >> 6][row] = p;
        __syncthreads();

        if (tid < 32) {
            float sum = gx;
            #pragma unroll
            for (int q = 0; q < 8; ++q) sum += partial[q][tid];
            // Per-lane activation, bitwise-identical formulas:
            // rows 0-7 i, 8-15 f (sigmoid), 16-23 g (tanh), 24-31 o (sigmoid)
            bool isg = ((tid >> 3) == 2);
            float e   = __expf(isg ? -2.f * sum : -sum);
            float act = isg ? (2.f / (1.f + e) - 1.f) : (1.f / (1.f + e));
            int jj = tid & 7;
            float sf = __shfl(act,  8 + jj, 64);
            float tg = __shfl(act, 16 + jj, 64);
            float so = __shfl(act, 24 + jj, 64);
            if (tid < 8) {
                float si = act;
                c = sf * c + si * tg;
                float th = 2.f / (1.f + __expf(-2.f * c)) - 1.f;
                float h = so * th;
                int j = g * JPW + tid;
                // agent-scope write-through: must be visible to other WGs'
                // fused fc phase (no kernel boundary anymore).
                __hip_atomic_store(h_all + (size_t)s * HD + j, h,
                                   __ATOMIC_RELAXED, __HIP_MEMORY_SCOPE_AGENT);
                u64 m = ((u64)(unsigned)(s + 1) << 32)
                      | (u64)__float_as_uint(h);
                u64* dst = h_msg + (size_t)((s + 1) & 1) * HD + j;
                if (s + 1 == SEQL)   // final publish: order h_all before tag
                    __hip_atomic_store(dst, m, __ATOMIC_RELEASE,
                                       __HIP_MEMORY_SCOPE_AGENT);
                else
                    __hip_atomic_store(dst, m, __ATOMIC_RELAXED,
                                       __HIP_MEMORY_SCOPE_AGENT);
            }
        }
    }

    // ---------------- fused FC tail: out[t0..t0+3][lab] ---------------------
    // Wait until ALL producers published tag 512 (parity 0), release-ordered
    // after their h_all writes.
    {
        const u64 addr = (u64)(h_msg + tid * 2);
        const unsigned want = (unsigned)SEQL;
        v4u ra;
        for (;;) {
            asm volatile(
                "global_load_dwordx4 %0, %1, off sc1\n\t"
                "s_waitcnt vmcnt(0)"
                : "=&v"(ra) : "v"(addr) : "memory");
            if (ra.y == want && ra.w == want) break;
            if (--budget < 0) break;
        }
    }
    __syncthreads();   // also: all waves done with gxs (step-loop reads)

    const int t0 = g * 4;
    // stage 4 rows of h (16 KB) into the gxs area via agent-scope loads
    float4* hst = (float4*)gxs;
    #pragma unroll
    for (int k = 0; k < 2; ++k) {
        int o4 = tid + k * 512;       // [0,1024)
        int tt = o4 >> 8;             // 0..3
        int idx = o4 & 255;
        const u64 ha = (u64)(h_all + (size_t)(t0 + tt) * HD + idx * 4);
        v4u hv;
        asm volatile(
            "global_load_dwordx4 %0, %1, off sc1\n\t"
            "s_waitcnt vmcnt(0)"
            : "=&v"(hv) : "v"(ha) : "memory");
        hst[o4] = (float4){__uint_as_float(hv.x), __uint_as_float(hv.y),
                           __uint_as_float(hv.z), __uint_as_float(hv.w)};
    }
    __syncthreads();

    if (tid < NLAB) {
        float b = b_fc[tid];
        float acc0 = b, acc1 = b, acc2 = b, acc3 = b;
        const float4* wp = (const float4*)(W_fc + (size_t)tid * HD);
        #pragma unroll 4
        for (int k4 = 0; k4 < 256; ++k4) {
            float4 w = wp[k4];
            float4 h0 = hst[k4];
            float4 h1 = hst[256 + k4];
            float4 h2 = hst[512 + k4];
            float4 h3 = hst[768 + k4];
            acc0 += w.x*h0.x + w.y*h0.y + w.z*h0.z + w.w*h0.w;
            acc1 += w.x*h1.x + w.y*h1.y + w.z*h1.z + w.w*h1.w;
            acc2 += w.x*h2.x + w.y*h2.y + w.z*h2.z + w.w*h2.w;
            acc3 += w.x*h3.x + w.y*h3.y + w.z*h3.z + w.w*h3.w;
        }
        out[(size_t)(t0 + 0) * NLAB + tid] = acc0;
        out[(size_t)(t0 + 1) * NLAB + tid] = acc1;
        out[(size_t)(t0 + 2) * NLAB + tid] = acc2;
        out[(size_t)(t0 + 3) * NLAB + tid] = acc3;
    }
}

// ---------------------------------------------------------------------------
extern "C" void kernel_launch(void* const* d_in, const int* in_sizes, int n_in,
                              void* d_out, int out_size, void* d_ws, size_t ws_size,
                              hipStream_t stream) {
    const float* x    = (const float*)d_in[0];
    const float* hi   = (const float*)d_in[1];
    const float* W_ih = (const float*)d_in[2];
    const float* W_hh = (const float*)d_in[3];
    const float* b_ih = (const float*)d_in[4];
    const float* b_hh = (const float*)d_in[5];
    const float* W_fc = (const float*)d_in[6];
    const float* b_fc = (const float*)d_in[7];
    float* out = (float*)d_out;

    char* ws = (char*)d_ws;
    u64*   h_msg   = (u64*)(ws + OFF_MSG);
    float* h_all   = (float*)(ws + OFF_HALL);
    float* gates_x = (float*)(ws + OFF_GATES);
    float* W_r2    = (float*)(ws + OFF_WR);
    uint4* W1h     = (uint4*)(ws + OFF_W1H);
    uint4* F_h     = (uint4*)(ws + OFF_FH);

    // 3 launches total: prep_all (incl. mailbox zero), gates GEMM, lstm+fc.
    if (ws_size >= WS_NEED) {
        prep_all<<<13313, 256, 0, stream>>>(x, hi, W_ih, W_hh, W_r2, F_h, W1h, h_msg);
        dim3 gg(32, 4);   // n-tiles x t-tiles
        gates_mfma<<<gg, 256, 0, stream>>>(F_h, W1h, b_ih, b_hh, gates_x);
    } else {
        // small-ws fallback: prep W_r2 + mailbox only, fp32 gates GEMM
        prep_all<<<4097, 256, 0, stream>>>(x, hi, W_ih, W_hh, W_r2, F_h, W1h, h_msg);
        dim3 gg(64, 8);
        gates_gemm_f32<<<gg, 256, 0, stream>>>(x, hi, W_ih, b_ih, b_hh, gates_x);
    }

    lstm_fc<<<NWG, TPW, 0, stream>>>(gates_x, W_r2, h_all, h_msg, W_fc, b_fc, out);
}

// Round 8
// 1170.847 us; speedup vs baseline: 1.1457x; 1.0641x over previous
//
#include <hip/hip_runtime.h>
#include <hip/hip_fp16.h>
#include <math.h>

// Problem constants
#define HD    1024      // hidden size
#define SEQL  512       // sequence length
#define NLAB  122       // labels
#define NWG   128       // workgroups in persistent recurrent kernel
#define TPW   512       // threads per WG
#define JPW   8         // h-columns (j) per workgroup  (NWG*JPW == HD)

// Workspace layout (bytes).
#define OFF_MSG   ((size_t)0)          // h msg: 2*1024 u64 (tag<<32|h_bits)    = 16384 B
#define OFF_HALL  ((size_t)16384)      // h_all: 512*1024 fp32                  = 2097152 B
#define OFF_GATES ((size_t)2113536)    // gates_x: 512*4096 fp32 (swizzled)     = 8388608 B
#define OFF_WR    ((size_t)10502144)   // W_r2: 4096*1024 fp32 (swizzled)       = 16777216 B
#define OFF_W1H   ((size_t)27279360)   // W1h: 4096*4096 fp16                   = 33554432 B
#define OFF_FH    ((size_t)60833792)   // F_h: 512*4096 fp16                    = 4194304 B
#define WS_NEED   ((size_t)65028096)

typedef unsigned long long u64;
typedef _Float16 v8h __attribute__((ext_vector_type(8)));
typedef float v4f __attribute__((ext_vector_type(4)));
typedef float v2f __attribute__((ext_vector_type(2)));
typedef unsigned int v4u __attribute__((ext_vector_type(4)));

// ---------------------------------------------------------------------------
// Merged prep (R11-proven): ONE launch for W_r2, mailbox zeroing, F_h, W1h.
//   b <  4096          : W_r2[g][i][t] = W_ih[.,4096+k] + W_hh  (R4 layout)
//   b == 4096          : zero h_msg (2048 u64)
//   4097 <= b < 5121   : F_h = fp16(concat(x,hi))
//   b >= 5121          : W1h = fp16(W_ih[:, :4096])
// Fallback (small ws) launches only 4097 blocks (no F_h/W1h writes).
static __device__ __forceinline__ uint4 pack8(float4 f0, float4 f1) {
    __half2 p0 = __floats2half2_rn(f0.x, f0.y);
    __half2 p1 = __floats2half2_rn(f0.z, f0.w);
    __half2 p2 = __floats2half2_rn(f1.x, f1.y);
    __half2 p3 = __floats2half2_rn(f1.z, f1.w);
    uint4 o;
    o.x = *(unsigned*)&p0; o.y = *(unsigned*)&p1;
    o.z = *(unsigned*)&p2; o.w = *(unsigned*)&p3;
    return o;
}

__global__ __launch_bounds__(256) void prep_all(const float* __restrict__ x,
                                                const float* __restrict__ hi,
                                                const float* __restrict__ W_ih,
                                                const float* __restrict__ W_hh,
                                                float* __restrict__ W_r2,
                                                uint4* __restrict__ F_h,
                                                uint4* __restrict__ W1h,
                                                u64* __restrict__ h_msg) {
    int b = blockIdx.x;
    int tid = threadIdx.x;
    if (b < 4096) {
        int o = b * 256 + tid;            // float4 index, < 1048576
        int g   = o >> 13;
        int i   = (o >> 9) & 15;
        int t   = o & 511;
        int row = t & 31;
        int kq  = t >> 5;
        int gate = row >> 3;
        int jj   = row & 7;
        int R = (gate << 10) + (g << 3) + jj;
        int k = (kq << 6) + (i << 2);
        float4 wa = *(const float4*)(W_ih + (size_t)R * 5120 + 4096 + k);
        float4 wb = *(const float4*)(W_hh + (size_t)R * 1024 + k);
        float4 out;
        out.x = wa.x + wb.x; out.y = wa.y + wb.y;
        out.z = wa.z + wb.z; out.w = wa.w + wb.w;
        *(float4*)(W_r2 + (size_t)o * 4) = out;
    } else if (b == 4096) {
        // mailbox zero: h_{-1}=0 with tag 0 (ws re-poisoned 0xAA each call)
        #pragma unroll
        for (int i = 0; i < 8; ++i)
            h_msg[tid * 8 + i] = 0ull;
    } else if (b < 5121) {
        int o = (b - 4097) * 256 + tid;   // < 262144
        int t = o >> 9;
        int u = o & 511;
        const float* src = (u < 256) ? (x  + (size_t)t * 2048 + u * 8)
                                     : (hi + (size_t)t * 2048 + (u - 256) * 8);
        F_h[o] = pack8(*(const float4*)src, *(const float4*)(src + 4));
    } else {
        int o = (b - 5121) * 256 + tid;   // < 2097152
        int r = o >> 9;
        int u = o & 511;
        const float* src = W_ih + (size_t)r * 5120 + u * 8;
        W1h[o] = pack8(*(const float4*)src, *(const float4*)(src + 4));
    }
}

// ---------------------------------------------------------------------------
// MFMA gates GEMM — R2-proven 4-wave version verbatim (0 bank conflicts).
// G[t][r] = bias[r] + sum_k F[t][k]*W1[r][k]; 128x128 tile, BK=32.
// Store to the R4-swizzled gates_x layout:
//   sidx(r) = ((r&1023)>>3)*32 + (r>>10)*8 + (r&7)
__global__ __launch_bounds__(256) void gates_mfma(const uint4* __restrict__ F_u4,
                                                  const uint4* __restrict__ W_u4,
                                                  const float* __restrict__ b_ih,
                                                  const float* __restrict__ b_hh,
                                                  float* __restrict__ gates_x) {
    __shared__ uint4 AsB[1024];          // As = [0,512), Bs = [512,1024)
    const _Float16* Ash = (const _Float16*)AsB;          // 4096 halfs
    const _Float16* Bsh = Ash + 4096;
    const int tid  = threadIdx.x;
    const int wv   = tid >> 6;
    const int lane = tid & 63;
    const int wr   = wv & 1;             // m quadrant
    const int wc   = wv >> 1;            // n quadrant
    const int n0 = blockIdx.x * 128;
    const int t0 = blockIdx.y * 128;

    // staging map: uint4 slot u in [0,512): row = u>>2, kpart = u&3
    const int u0 = tid * 2, u1 = tid * 2 + 1;
    const uint4* aSrc0 = F_u4 + (size_t)(t0 + (u0 >> 2)) * 512 + (u0 & 3);
    const uint4* aSrc1 = F_u4 + (size_t)(t0 + (u1 >> 2)) * 512 + (u1 & 3);
    const uint4* bSrc0 = W_u4 + (size_t)(n0 + (u0 >> 2)) * 512 + (u0 & 3);
    const uint4* bSrc1 = W_u4 + (size_t)(n0 + (u1 >> 2)) * 512 + (u1 & 3);

    v4f acc[4][4];
    #pragma unroll
    for (int mi = 0; mi < 4; ++mi)
        #pragma unroll
        for (int ni = 0; ni < 4; ++ni)
            acc[mi][ni] = (v4f){0.f, 0.f, 0.f, 0.f};

    const int aoff = (wr * 64 + (lane & 15)) * 32 + (lane >> 4) * 8;
    const int boff = (wc * 64 + (lane & 15)) * 32 + (lane >> 4) * 8;

    for (int it = 0; it < 128; ++it) {    // kb = it*32, advance 4 uint4/row
        uint4 a0 = aSrc0[it * 4], a1 = aSrc1[it * 4];
        uint4 b0 = bSrc0[it * 4], b1 = bSrc1[it * 4];
        __syncthreads();                  // prior iter's frag reads done
        AsB[u0]       = a0; AsB[u1]       = a1;
        AsB[512 + u0] = b0; AsB[512 + u1] = b1;
        __syncthreads();
        v8h a8[4], b8[4];
        #pragma unroll
        for (int mi = 0; mi < 4; ++mi)
            a8[mi] = *(const v8h*)(Ash + aoff + mi * 16 * 32);
        #pragma unroll
        for (int ni = 0; ni < 4; ++ni)
            b8[ni] = *(const v8h*)(Bsh + boff + ni * 16 * 32);
        #pragma unroll
        for (int mi = 0; mi < 4; ++mi)
            #pragma unroll
            for (int ni = 0; ni < 4; ++ni)
                acc[mi][ni] = __builtin_amdgcn_mfma_f32_16x16x32_f16(
                                  a8[mi], b8[ni], acc[mi][ni], 0, 0, 0);
    }

    // epilogue: C row (t) = t0 + wr*64 + mi*16 + (lane>>4)*4 + reg
    //           C col (r) = n0 + wc*64 + ni*16 + (lane&15)
    #pragma unroll
    for (int ni = 0; ni < 4; ++ni) {
        int r = n0 + wc * 64 + ni * 16 + (lane & 15);
        int sidx = ((r & 1023) >> 3) * 32 + (r >> 10) * 8 + (r & 7);
        float bias = b_ih[r] + b_hh[r];
        #pragma unroll
        for (int mi = 0; mi < 4; ++mi) {
            int tb = t0 + wr * 64 + mi * 16 + ((lane >> 4) << 2);
            #pragma unroll
            for (int reg = 0; reg < 4; ++reg)
                gates_x[(size_t)(tb + reg) * 4096 + sidx] = acc[mi][ni][reg] + bias;
        }
    }
}

// ---------------------------------------------------------------------------
// Fallback fp32 VALU gates GEMM (used only if ws_size < WS_NEED).
__global__ __launch_bounds__(256) void gates_gemm_f32(const float* __restrict__ x,
                                                      const float* __restrict__ hi,
                                                      const float* __restrict__ W_ih,
                                                      const float* __restrict__ b_ih,
                                                      const float* __restrict__ b_hh,
                                                      float* __restrict__ gates_x) {
    __shared__ float As[16][68];
    __shared__ float Bs[16][68];
    const int tid = threadIdx.x;
    const int r0 = blockIdx.x * 64;
    const int t0 = blockIdx.y * 64;
    const int tx = tid & 15, ty = tid >> 4;
    const int l   = tid & 63;
    const int kq4 = tid >> 6;

    float acc[4][4] = {};
    for (int kb = 0; kb < 4096; kb += 16) {
        int k = kb + kq4 * 4;
        const float* asrc = (k < 2048) ? (x  + (size_t)(t0 + l) * 2048 + k)
                                       : (hi + (size_t)(t0 + l) * 2048 + (k - 2048));
        float4 a4 = *(const float4*)asrc;
        float4 b4 = *(const float4*)(W_ih + (size_t)(r0 + l) * 5120 + k);
        __syncthreads();
        As[kq4 * 4 + 0][l] = a4.x; As[kq4 * 4 + 1][l] = a4.y;
        As[kq4 * 4 + 2][l] = a4.z; As[kq4 * 4 + 3][l] = a4.w;
        Bs[kq4 * 4 + 0][l] = b4.x; Bs[kq4 * 4 + 1][l] = b4.y;
        Bs[kq4 * 4 + 2][l] = b4.z; Bs[kq4 * 4 + 3][l] = b4.w;
        __syncthreads();
        #pragma unroll
        for (int kk = 0; kk < 16; ++kk) {
            float4 av = *(const float4*)&As[kk][ty * 4];
            float4 bv = *(const float4*)&Bs[kk][tx * 4];
            float a_[4] = {av.x, av.y, av.z, av.w};
            float b_[4] = {bv.x, bv.y, bv.z, bv.w};
            #pragma unroll
            for (int i = 0; i < 4; ++i)
                #pragma unroll
                for (int j = 0; j < 4; ++j)
                    acc[i][j] += a_[i] * b_[j];
        }
    }
    int r = r0 + tx * 4;
    float bias[4];
    #pragma unroll
    for (int j = 0; j < 4; ++j) bias[j] = b_ih[r + j] + b_hh[r + j];
    int gate = r >> 10;
    int g    = (r & 1023) >> 3;
    int jj   = r & 7;
    int sidx = g * 32 + gate * 8 + jj;
    #pragma unroll
    for (int i = 0; i < 4; ++i) {
        float4 o;
        o.x = acc[i][0] + bias[0]; o.y = acc[i][1] + bias[1];
        o.z = acc[i][2] + bias[2]; o.w = acc[i][3] + bias[3];
        *(float4*)(gates_x + (size_t)(t0 + ty * 4 + i) * 4096 + sidx) = o;
    }
}

// ---------------------------------------------------------------------------
// Persistent recurrent kernel — R5 VERBATIM (best measured: 886 us, VGPR 56,
// LDS 71168). R7-R11 modifications all regressed; byte-identical restore.
//   (1) gates_x slice (64 KB) pre-staged to LDS; per-step gx is an LDS hit.
//   (2) weights hoisted at source level (compiler sinks to per-step global
//       reloads -> VGPR 56; measured FASTER than the LDS-weight variant).
//   (3) poll: two back-to-back coalesced dwordx4 sc1 samples, fully drained.
//   (4) wave-local h exchange: each wave's 64 lanes poll exactly the 128
//       h-values its own matvec consumes; same-wave DS ops are in-order ->
//       no pre-matvec barrier.
//   (5) per-lane activations (bitwise-identical formulas) before shuffles.
//   Safety of the single barrier: wave w's partial[] write for step s+1
//   requires a remote step-s+1 publication, which transitively requires our
//   WG's step-s publication, which wave0 issues only after reading partials.
__global__ __launch_bounds__(512, 1) void lstm_rec(const float* __restrict__ gates_x,
                                                   const float* __restrict__ W_r2,
                                                   float* __restrict__ h_all,
                                                   u64* h_msg) {
    const int g   = blockIdx.x;
    const int tid = threadIdx.x;
    const int row = tid & 31;    // gate = row>>3, jj = row&7
    const int kq  = tid >> 5;    // k-slice [kq*64, kq*64+64)
    __shared__ float  gxs[SEQL * 32];   // 64 KB: this WG's gates for all steps
    __shared__ float4 h_s4[256];        // h_{s-1}; h_s4[q] = h[4q..4q+3]
    __shared__ float  partial[8][36];   // [wave][row]
    float* h_sf = (float*)h_s4;

    // Weights resident in VGPRs for the whole kernel (64 VGPRs).
    float4 w[16];
    {
        const float4* Wp = (const float4*)W_r2 + (size_t)g * 8192;
        #pragma unroll
        for (int i = 0; i < 16; ++i)
            w[i] = Wp[i * TPW + tid];
    }

    // Stage this WG's gates_x slice (512 steps x 32 rows) into LDS.
    {
        float4* gxs4 = (float4*)gxs;
        const float* gsrc = gates_x + (size_t)g * 32;
        #pragma unroll
        for (int k = 0; k < 8; ++k) {
            int o4 = tid + k * 512;           // [0, 4096)
            int s  = o4 >> 3, c4 = o4 & 7;
            gxs4[o4] = *(const float4*)(gsrc + (size_t)s * 4096 + c4 * 4);
        }
    }
    __syncthreads();

    float c = 0.f;
    int budget = 4000000;

    for (int s = 0; s < SEQL; ++s) {
        float gx = 0.f;
        if (tid < 32) gx = gxs[s * 32 + tid];

        // Poll own 2 mailbox words: one coalesced 16B device-scope load per
        // sample (wave covers a contiguous 1 KiB span -> 16 full lines).
        {
            const u64 addr = (u64)(h_msg + (size_t)(s & 1) * HD + tid * 2);
            const unsigned want = (unsigned)s;
            v4u ra, rb;
            for (;;) {
                asm volatile(
                    "global_load_dwordx4 %0, %2, off sc1\n\t"
                    "global_load_dwordx4 %1, %2, off sc1\n\t"
                    "s_waitcnt vmcnt(0)"
                    : "=&v"(ra), "=&v"(rb)
                    : "v"(addr)
                    : "memory");
                if (ra.y == want && ra.w == want) break;
                if (rb.y == want && rb.w == want) { ra = rb; break; }
                if (--budget < 0) { ra = rb; break; }
            }
            ((v2f*)h_sf)[tid] = (v2f){__uint_as_float(ra.x), __uint_as_float(ra.z)};
        }
        // Wave-local exchange: this wave's lanes wrote exactly the 128 floats
        // this wave's matvec reads; same-wave DS ops execute in order, so no
        // barrier — only a compiler reordering fence.
        asm volatile("" ::: "memory");

        float a0 = 0.f, a1 = 0.f, a2 = 0.f, a3 = 0.f;
        #pragma unroll
        for (int i = 0; i < 16; ++i) {
            float4 h4 = h_s4[kq * 16 + i];
            a0 += w[i].x * h4.x;
            a1 += w[i].y * h4.y;
            a2 += w[i].z * h4.z;
            a3 += w[i].w * h4.w;
        }
        float p = (a0 + a1) + (a2 + a3);
        p += __shfl_xor(p, 32, 64);
        if ((tid & 32) == 0)
            partial[tid >> 6][row] = p;
        __syncthreads();

        if (tid < 32) {
            float sum = gx;
            #pragma unroll
            for (int q = 0; q < 8; ++q) sum += partial[q][tid];
            // Per-lane activation, bitwise-identical formulas:
            // rows 0-7 i, 8-15 f (sigmoid), 16-23 g (tanh), 24-31 o (sigmoid)
            bool isg = ((tid >> 3) == 2);
            float e   = __expf(isg ? -2.f * sum : -sum);
            float act = isg ? (2.f / (1.f + e) - 1.f) : (1.f / (1.f + e));
            int jj = tid & 7;
            float sf = __shfl(act,  8 + jj, 64);
            float tg = __shfl(act, 16 + jj, 64);
            float so = __shfl(act, 24 + jj, 64);
            if (tid < 8) {
                float si = act;
                c = sf * c + si * tg;
                float th = 2.f / (1.f + __expf(-2.f * c)) - 1.f;
                float h = so * th;
                int j = g * JPW + tid;
                h_all[(size_t)s * HD + j] = h;
                u64 m = ((u64)(unsigned)(s + 1) << 32)
                      | (u64)__float_as_uint(h);
                __hip_atomic_store(h_msg + (size_t)((s + 1) & 1) * HD + j, m,
                                   __ATOMIC_RELAXED, __HIP_MEMORY_SCOPE_AGENT);
            }
        }
    }
}

// ---------------------------------------------------------------------------
// out[t][lab] = b_fc[lab] + sum_k h_all[t][k] * W_fc[lab][k]
// 4 timesteps per block: W_fc global traffic /4 vs the 1-t version.
__global__ __launch_bounds__(128) void fc_out(const float* __restrict__ h_all,
                                              const float* __restrict__ W_fc,
                                              const float* __restrict__ b_fc,
                                              float* __restrict__ out) {
    const int t0 = blockIdx.x * 4;          // 128 blocks x 4 t
    const int tid = threadIdx.x;
    __shared__ float4 h_s[1024];            // 16 KB: 4 rows of h
    const float4* hsrc = (const float4*)(h_all + (size_t)t0 * HD);
    #pragma unroll
    for (int i = 0; i < 8; ++i)
        h_s[tid + i * 128] = hsrc[tid + i * 128];
    __syncthreads();
    if (tid < NLAB) {
        float b = b_fc[tid];
        float acc0 = b, acc1 = b, acc2 = b, acc3 = b;
        const float4* wp = (const float4*)(W_fc + (size_t)tid * HD);
        #pragma unroll 4
        for (int k4 = 0; k4 < 256; ++k4) {
            float4 w = wp[k4];
            float4 h0 = h_s[k4];
            float4 h1 = h_s[256 + k4];
            float4 h2 = h_s[512 + k4];
            float4 h3 = h_s[768 + k4];
            acc0 += w.x*h0.x + w.y*h0.y + w.z*h0.z + w.w*h0.w;
            acc1 += w.x*h1.x + w.y*h1.y + w.z*h1.z + w.w*h1.w;
            acc2 += w.x*h2.x + w.y*h2.y + w.z*h2.z + w.w*h2.w;
            acc3 += w.x*h3.x + w.y*h3.y + w.z*h3.z + w.w*h3.w;
        }
        out[(size_t)(t0 + 0) * NLAB + tid] = acc0;
        out[(size_t)(t0 + 1) * NLAB + tid] = acc1;
        out[(size_t)(t0 + 2) * NLAB + tid] = acc2;
        out[(size_t)(t0 + 3) * NLAB + tid] = acc3;
    }
}

// ---------------------------------------------------------------------------
extern "C" void kernel_launch(void* const* d_in, const int* in_sizes, int n_in,
                              void* d_out, int out_size, void* d_ws, size_t ws_size,
                              hipStream_t stream) {
    const float* x    = (const float*)d_in[0];
    const float* hi   = (const float*)d_in[1];
    const float* W_ih = (const float*)d_in[2];
    const float* W_hh = (const float*)d_in[3];
    const float* b_ih = (const float*)d_in[4];
    const float* b_hh = (const float*)d_in[5];
    const float* W_fc = (const float*)d_in[6];
    const float* b_fc = (const float*)d_in[7];
    float* out = (float*)d_out;

    char* ws = (char*)d_ws;
    u64*   h_msg   = (u64*)(ws + OFF_MSG);
    float* h_all   = (float*)(ws + OFF_HALL);
    float* gates_x = (float*)(ws + OFF_GATES);
    float* W_r2    = (float*)(ws + OFF_WR);
    uint4* W1h     = (uint4*)(ws + OFF_W1H);
    uint4* F_h     = (uint4*)(ws + OFF_FH);

    // 4 launches: prep_all (incl. mailbox zero), gates GEMM, lstm, fc.
    if (ws_size >= WS_NEED) {
        prep_all<<<13313, 256, 0, stream>>>(x, hi, W_ih, W_hh, W_r2, F_h, W1h, h_msg);
        dim3 gg(32, 4);   // n-tiles x t-tiles
        gates_mfma<<<gg, 256, 0, stream>>>(F_h, W1h, b_ih, b_hh, gates_x);
    } else {
        // small-ws fallback: prep W_r2 + mailbox only, fp32 gates GEMM
        prep_all<<<4097, 256, 0, stream>>>(x, hi, W_ih, W_hh, W_r2, F_h, W1h, h_msg);
        dim3 gg(64, 8);
        gates_gemm_f32<<<gg, 256, 0, stream>>>(x, hi, W_ih, b_ih, b_hh, gates_x);
    }

    lstm_rec<<<NWG, TPW, 0, stream>>>(gates_x, W_r2, h_all, h_msg);

    fc_out<<<SEQL / 4, 128, 0, stream>>>(h_all, W_fc, b_fc, out);
}